// Round 5
// baseline (148.448 us; speedup 1.0000x reference)
//
#include <hip/hip_runtime.h>
#include <math.h>

#define HH 300
#define WW 300
#define CC 4
#define MM 4096
#define KP 640          // padded K (fp8: 640 bytes/row), 2*W=600 -> 640
#define CSTRIDE 384     // per-coil row stride (3*128: every 128-row tile coil-pure)
#define MP (CC*CSTRIDE) // 1536
#define NP 8192         // 2*M (real | imag output columns)
#define BK 128          // K-chunk per iteration (one mfma_scale per 16x16 tile)
#define NRB (MP/128)    // 12 row-blocks
#define NBLK ((NP/128)*(MP/128))   // 768 gemm blocks

typedef __attribute__((ext_vector_type(4))) float f32x4;
typedef __attribute__((ext_vector_type(4))) int int4v;
typedef __attribute__((ext_vector_type(8))) int int8v;
typedef const __attribute__((address_space(1))) void g_void;
typedef __attribute__((address_space(3))) void l_void;

#define TWO_PI 6.283185307179586f

// A value at (row, k): row = c*CSTRIDE + h; k<300 -> sim_r[w=k]; 300<=k<600 -> sim_i; else 0
__device__ __forceinline__ float aval(const float* img, const float* csm,
                                      int c, int h, int k) {
    if (k >= 2 * WW) return 0.0f;
    int w = (k < WW) ? k : k - WW;
    float im = img[h * WW + w];
    const float* cs = csm + (((size_t)c * HH + h) * WW + w) * 2;
    return ((k < WW) ? cs[0] : cs[1]) * im;
}

// prep: zero the gemm completion counter, build A (MP x KP fp8 e4m3),
// build B^T (NP x KP fp8). B structure: row m (real col) = [ez_r | -ez_i | 0pad],
// row m+4096 (imag col) = [ez_i | ez_r | 0pad]. One thread computes one w-pair's
// sincos and writes all 4 destinations (4x dedup vs round 4).
__global__ __launch_bounds__(256) void prep_kernel(
    const float* __restrict__ img, const float* __restrict__ csm,
    const float* __restrict__ omega, ushort* __restrict__ A,
    unsigned char* __restrict__ B, int* __restrict__ counter)
{
    const int bid = blockIdx.x;
    if (bid == 0 && threadIdx.x == 0) *counter = 0;
    const int ABLK = (MP * KP / 2) / 256;   // 1920
    if (bid < ABLK) {
        int idx = bid * 256 + threadIdx.x;            // pair index
        int row = idx / (KP / 2);
        int k   = (idx - row * (KP / 2)) * 2;
        int c = row / CSTRIDE;
        int h = row - c * CSTRIDE;
        float v0 = 0.0f, v1 = 0.0f;
        if (h < HH) { v0 = aval(img, csm, c, h, k); v1 = aval(img, csm, c, h, k + 1); }
        int pk = __builtin_amdgcn_cvt_pk_fp8_f32(v0, v1, 0, false);
        A[idx] = (ushort)pk;
    } else {
        // B: 160 threads per m: wp<150 -> w-pair (w=2*wp, w+1); wp in [150,160) -> pad zeros
        int idx = (bid - ABLK) * 256 + threadIdx.x;   // 0 .. 4096*160-1
        int m  = idx / 160;
        int wp = idx - m * 160;
        unsigned char* r0 = B + (size_t)m * KP;            // real col row
        unsigned char* r1 = B + (size_t)(m + MM) * KP;     // imag col row
        if (wp < 150) {
            int w = wp * 2;
            float om1 = omega[MM + m];
            float s0, c0, s1, c1;
            __sincosf(TWO_PI * om1 * (float)(w - 150), &s0, &c0);
            __sincosf(TWO_PI * om1 * (float)(w - 149), &s1, &c1);
            // ez = exp(-i th): ez_r = cos, ez_i = -sin
            ushort rr = (ushort)__builtin_amdgcn_cvt_pk_fp8_f32(c0, c1, 0, false);
            ushort ii = (ushort)__builtin_amdgcn_cvt_pk_fp8_f32(-s0, -s1, 0, false);
            ushort ni = (ushort)__builtin_amdgcn_cvt_pk_fp8_f32(s0, s1, 0, false); // -ez_i
            *(ushort*)(r0 + w)       = rr;   // real col, k in [0,300)
            *(ushort*)(r0 + WW + w)  = ni;   // real col, k in [300,600): -ez_i
            *(ushort*)(r1 + w)       = ii;   // imag col, k in [0,300):  ez_i
            *(ushort*)(r1 + WW + w)  = rr;   // imag col, k in [300,600): ez_r
        } else {
            int z = (wp - 150) * 4;
            *(unsigned int*)(r0 + 600 + z) = 0u;
            *(unsigned int*)(r1 + 600 + z) = 0u;
        }
    }
}

// fp8 MX GEMM (128x128 tile, BK=128, unit scales) + fused ey-rotation epilogue
// + last-block loss computation. XCD-swizzled grid for L2 locality.
__global__ __launch_bounds__(256) void gemm_kernel(
    const unsigned char* __restrict__ A, const unsigned char* __restrict__ B,
    const float* __restrict__ omega, const float* __restrict__ kdata,
    float2* __restrict__ P, int* __restrict__ counter, float* __restrict__ out)
{
    __shared__ unsigned char As[128 * BK];
    __shared__ unsigned char Bs[128 * BK];
    __shared__ float2 red[128];
    __shared__ float wred[4];
    __shared__ int lastflag;

    const int t    = threadIdx.x;
    const int wave = t >> 6;
    const int ln   = t & 63;

    // XCD swizzle: xcd = bid&7 owns col-tiles [8*xcd, 8*xcd+8) x all 12 row-tiles.
    // Working set per XCD: full A (0.98 MB) + 8 B-cols (0.66 MB) < 4 MiB L2.
    const int bid = blockIdx.x;
    const int xcd = bid & 7;
    const int sub = bid >> 3;            // 0..95
    const int row0 = (sub >> 3) * 128;   // 12 row-tiles
    const int col0 = (xcd * 8 + (sub & 7)) * 128;

    const int wr = wave >> 1, wc = wave & 1;
    const int lr = ln & 15;
    const int lq = ln >> 4;

    if (t < 128) red[t] = make_float2(0.0f, 0.0f);

    // staging: pass p covers rows p*32..p*32+31 (128 B/row). XOR swizzle on the
    // global source so fragment ds_read_b128 is 2-way (free).
    const int srow  = t >> 3;
    const int cphys = (t >> 1) & 3;
    const int half  = t & 1;
    const int sgoff = ((cphys ^ (srow & 3)) << 5) + (half << 4);

    f32x4 acc[4][4] = {};

    for (int k0 = 0; k0 < KP; k0 += BK) {
        #pragma unroll
        for (int p = 0; p < 4; ++p) {
            const unsigned char* gA = A + (size_t)(row0 + p * 32 + srow) * KP + k0 + sgoff;
            const unsigned char* gB = B + (size_t)(col0 + p * 32 + srow) * KP + k0 + sgoff;
            __builtin_amdgcn_global_load_lds((g_void*)gA, (l_void*)(As + p * 4096 + t * 16), 16, 0, 0);
            __builtin_amdgcn_global_load_lds((g_void*)gB, (l_void*)(Bs + p * 4096 + t * 16), 16, 0, 0);
        }
        __syncthreads();

        int8v a[4], b[4];
        #pragma unroll
        for (int i = 0; i < 4; ++i) {
            const int r = wr * 64 + i * 16 + lr;
            const unsigned char* pA = As + r * BK + ((lq ^ (lr & 3)) << 5);
            int4v lo = *(const int4v*)pA;
            int4v hi = *(const int4v*)(pA + 16);
            a[i] = __builtin_shufflevector(lo, hi, 0, 1, 2, 3, 4, 5, 6, 7);
        }
        #pragma unroll
        for (int j = 0; j < 4; ++j) {
            const int r = wc * 64 + j * 16 + lr;
            const unsigned char* pB = Bs + r * BK + ((lq ^ (lr & 3)) << 5);
            int4v lo = *(const int4v*)pB;
            int4v hi = *(const int4v*)(pB + 16);
            b[j] = __builtin_shufflevector(lo, hi, 0, 1, 2, 3, 4, 5, 6, 7);
        }
        #pragma unroll
        for (int i = 0; i < 4; ++i)
            #pragma unroll
            for (int j = 0; j < 4; ++j)
                acc[i][j] = __builtin_amdgcn_mfma_scale_f32_16x16x128_f8f6f4(
                    a[i], b[j], acc[i][j], 0, 0,      // cbsz=0 (fp8), blgp=0 (fp8)
                    0, 0x7f7f7f7f, 0, 0x7f7f7f7f);    // unit E8M0 scales
        __syncthreads();
    }

    // ---- fused stage-2 epilogue: P[rb][col] = sum_h acc * ey(m,h) ----
    const int c  = row0 / CSTRIDE;   // block-uniform (CSTRIDE = 3*128)
    const int h0 = row0 - c * CSTRIDE;

    #pragma unroll
    for (int j = 0; j < 4; ++j) {
        const int jcol = wc * 64 + j * 16 + lr;
        const int m = (col0 + jcol) & (MM - 1);
        const float om0 = omega[m];
        float ss, sc;
        __sincosf(TWO_PI * om0, &ss, &sc);
        const float str = sc, sti = -ss;               // exp(-2pi i om0)
        float pr = 0.0f, pi = 0.0f;
        #pragma unroll
        for (int i = 0; i < 4; ++i) {
            const int hb = h0 + wr * 64 + i * 16 + lq * 4;
            float sn, cs;
            __sincosf(TWO_PI * om0 * (float)(hb - 150), &sn, &cs);
            float er = cs, ei = -sn;                   // ey at h = hb
            #pragma unroll
            for (int r = 0; r < 4; ++r) {
                const float v = acc[i][j][r];
                pr = fmaf(v, er, pr);
                pi = fmaf(v, ei, pi);
                float nr = er * str - ei * sti;
                ei = er * sti + ei * str;
                er = nr;
            }
        }
        pr += __shfl_down(pr, 32); pi += __shfl_down(pi, 32);
        pr += __shfl_down(pr, 16); pi += __shfl_down(pi, 16);
        if (lq == 0) {
            atomicAdd(&red[jcol].x, pr);
            atomicAdd(&red[jcol].y, pi);
        }
    }
    __syncthreads();

    if (t < 128) {
        const int rb = row0 >> 7;
        P[(size_t)rb * NP + col0 + t] = red[t];
    }
    __syncthreads();                 // drains the P stores (vmcnt 0 at barrier)

    // ---- last-finishing block computes the loss ----
    if (t == 0) {
        __threadfence();             // release: write back this XCD's L2
        int old = atomicAdd(counter, 1);
        lastflag = (old == NBLK - 1);
    }
    __syncthreads();
    if (!lastflag) return;
    __threadfence();                 // acquire: invalidate local caches

    float vsum = 0.0f;
    for (int idx = t; idx < CC * MM; idx += 256) {
        const int cc = idx >> 12;
        const int m  = idx & (MM - 1);
        float kr = 0.0f, ki = 0.0f;
        #pragma unroll
        for (int q = 0; q < 3; ++q) {
            const int rb = 3 * cc + q;
            float2 p0 = P[(size_t)rb * NP + m];
            float2 p1 = P[(size_t)rb * NP + m + MM];
            kr += p0.x - p1.y;
            ki += p0.y + p1.x;
        }
        kr *= (1.0f / 300.0f);
        ki *= (1.0f / 300.0f);
        const float o0 = omega[m];
        const float o1 = omega[MM + m];
        const size_t kidx = ((size_t)cc * MM + m) * 2;
        const float kdr = kdata[kidx];
        const float kdi = kdata[kidx + 1];
        const float w0 = o0 * TWO_PI, w1 = o1 * TWO_PI;
        const float wg = sqrtf(w0 * w0 + w1 * w1) + 1.0f;
        const float dr = wg * (kr - kdr);
        const float di = wg * (ki - kdi);
        vsum += (dr * dr + di * di) * (1.0f / (2.0f * CC * MM));
    }
    #pragma unroll
    for (int off = 32; off > 0; off >>= 1) vsum += __shfl_down(vsum, off);
    if (ln == 0) wred[wave] = vsum;
    __syncthreads();
    if (t == 0) out[0] = wred[0] + wred[1] + wred[2] + wred[3];
}

extern "C" void kernel_launch(void* const* d_in, const int* in_sizes, int n_in,
                              void* d_out, int out_size, void* d_ws, size_t ws_size,
                              hipStream_t stream) {
    const float* img   = (const float*)d_in[0];   // (300,300,1)
    const float* kdata = (const float*)d_in[1];   // (1,4,4096,2)
    const float* omega = (const float*)d_in[2];   // (1,2,4096)
    const float* csm   = (const float*)d_in[4];   // (4,300,300,2)
    float* out = (float*)d_out;

    unsigned char* Aws = (unsigned char*)d_ws;                  // MP*KP  = 0.98 MB
    unsigned char* Bws = (unsigned char*)d_ws + (1u << 20);     // NP*KP  = 5.24 MB
    float2*        Pws = (float2*)((char*)d_ws + (8u << 20));   // NRB*NP*8 = 786 KB
    int*           cnt = (int*)((char*)d_ws + (16u << 20));

    const int ablk = (MP * KP / 2) / 256;      // 1920
    const int bblk = (MM * 160) / 256;         // 2560
    prep_kernel<<<ablk + bblk, 256, 0, stream>>>(img, csm, omega,
                                                 (ushort*)Aws, Bws, cnt);
    gemm_kernel<<<NBLK, 256, 0, stream>>>(Aws, Bws, omega, kdata, Pws, cnt, out);
}

// Round 6
// 89.773 us; speedup vs baseline: 1.6536x; 1.6536x over previous
//
#include <hip/hip_runtime.h>
#include <math.h>

#define HH 300
#define WW 300
#define CC 4
#define MM 4096
#define KP 640          // padded K (fp8: 640 bytes/row), 2*W=600 -> 640
#define CSTRIDE 384     // per-coil row stride (3*128: every 128-row tile coil-pure)
#define MP (CC*CSTRIDE) // 1536
#define NP 8192         // 2*M (real | imag output columns)
#define BK 128          // K-chunk per iteration (one mfma_scale per 16x16 tile)
#define NRB (MP/128)    // 12 row-blocks

typedef __attribute__((ext_vector_type(4))) float f32x4;
typedef __attribute__((ext_vector_type(4))) int int4v;
typedef __attribute__((ext_vector_type(8))) int int8v;
typedef const __attribute__((address_space(1))) void g_void;
typedef __attribute__((address_space(3))) void l_void;

#define TWO_PI 6.283185307179586f

// A value at (row, k): row = c*CSTRIDE + h; k<300 -> sim_r[w=k]; 300<=k<600 -> sim_i; else 0
__device__ __forceinline__ float aval(const float* img, const float* csm,
                                      int c, int h, int k) {
    if (k >= 2 * WW) return 0.0f;
    int w = (k < WW) ? k : k - WW;
    float im = img[h * WW + w];
    const float* cs = csm + (((size_t)c * HH + h) * WW + w) * 2;
    return ((k < WW) ? cs[0] : cs[1]) * im;
}

// prep: zero out[0], build A (MP x KP fp8 e4m3), build B^T (NP x KP fp8).
// B row m (real col) = [ez_r | -ez_i | 0pad]; row m+4096 (imag col) = [ez_i | ez_r | 0pad].
// One thread computes one w-pair's sincos and writes all 4 destinations (4x dedup).
__global__ __launch_bounds__(256) void prep_kernel(
    const float* __restrict__ img, const float* __restrict__ csm,
    const float* __restrict__ omega, ushort* __restrict__ A,
    unsigned char* __restrict__ B, float* __restrict__ out)
{
    const int bid = blockIdx.x;
    if (bid == 0 && threadIdx.x == 0) out[0] = 0.0f;
    const int ABLK = (MP * KP / 2) / 256;   // 1920
    if (bid < ABLK) {
        int idx = bid * 256 + threadIdx.x;            // pair index
        int row = idx / (KP / 2);
        int k   = (idx - row * (KP / 2)) * 2;
        int c = row / CSTRIDE;
        int h = row - c * CSTRIDE;
        float v0 = 0.0f, v1 = 0.0f;
        if (h < HH) { v0 = aval(img, csm, c, h, k); v1 = aval(img, csm, c, h, k + 1); }
        int pk = __builtin_amdgcn_cvt_pk_fp8_f32(v0, v1, 0, false);
        A[idx] = (ushort)pk;
    } else {
        // B: 160 threads per m: wp<150 -> w-pair (w=2*wp, w+1); wp in [150,160) -> pad zeros
        int idx = (bid - ABLK) * 256 + threadIdx.x;   // 0 .. 4096*160-1
        int m  = idx / 160;
        int wp = idx - m * 160;
        unsigned char* r0 = B + (size_t)m * KP;            // real col row
        unsigned char* r1 = B + (size_t)(m + MM) * KP;     // imag col row
        if (wp < 150) {
            int w = wp * 2;
            float om1 = omega[MM + m];
            float s0, c0, s1, c1;
            __sincosf(TWO_PI * om1 * (float)(w - 150), &s0, &c0);
            __sincosf(TWO_PI * om1 * (float)(w - 149), &s1, &c1);
            // ez = exp(-i th): ez_r = cos, ez_i = -sin
            ushort rr = (ushort)__builtin_amdgcn_cvt_pk_fp8_f32(c0, c1, 0, false);
            ushort ii = (ushort)__builtin_amdgcn_cvt_pk_fp8_f32(-s0, -s1, 0, false);
            ushort ni = (ushort)__builtin_amdgcn_cvt_pk_fp8_f32(s0, s1, 0, false); // -ez_i
            *(ushort*)(r0 + w)       = rr;   // real col, k in [0,300)
            *(ushort*)(r0 + WW + w)  = ni;   // real col, k in [300,600): -ez_i
            *(ushort*)(r1 + w)       = ii;   // imag col, k in [0,300):  ez_i
            *(ushort*)(r1 + WW + w)  = rr;   // imag col, k in [300,600): ez_r
        } else {
            int z = (wp - 150) * 4;
            *(unsigned int*)(r0 + 600 + z) = 0u;
            *(unsigned int*)(r1 + 600 + z) = 0u;
        }
    }
}

// fp8 MX GEMM (128x128 tile, BK=128, unit scales) + fused ey-rotation epilogue.
// 2D grid (col-tile fast) -> col-tiles round-robin across XCDs = good L2 locality.
__global__ __launch_bounds__(256) void gemm_kernel(
    const unsigned char* __restrict__ A, const unsigned char* __restrict__ B,
    const float* __restrict__ omega, float2* __restrict__ P)
{
    __shared__ unsigned char As[128 * BK];
    __shared__ unsigned char Bs[128 * BK];
    __shared__ float2 red[128];

    const int t    = threadIdx.x;
    const int wave = t >> 6;
    const int ln   = t & 63;
    const int row0 = blockIdx.y * 128;
    const int col0 = blockIdx.x * 128;
    const int wr = wave >> 1, wc = wave & 1;
    const int lr = ln & 15;
    const int lq = ln >> 4;

    if (t < 128) red[t] = make_float2(0.0f, 0.0f);

    // staging: pass p covers rows p*32..p*32+31 (128 B/row). XOR swizzle on the
    // global source so fragment ds_read_b128 is 2-way (free, m136).
    const int srow  = t >> 3;
    const int cphys = (t >> 1) & 3;
    const int half  = t & 1;
    const int sgoff = ((cphys ^ (srow & 3)) << 5) + (half << 4);

    f32x4 acc[4][4] = {};

    for (int k0 = 0; k0 < KP; k0 += BK) {
        #pragma unroll
        for (int p = 0; p < 4; ++p) {
            const unsigned char* gA = A + (size_t)(row0 + p * 32 + srow) * KP + k0 + sgoff;
            const unsigned char* gB = B + (size_t)(col0 + p * 32 + srow) * KP + k0 + sgoff;
            __builtin_amdgcn_global_load_lds((g_void*)gA, (l_void*)(As + p * 4096 + t * 16), 16, 0, 0);
            __builtin_amdgcn_global_load_lds((g_void*)gB, (l_void*)(Bs + p * 4096 + t * 16), 16, 0, 0);
        }
        __syncthreads();

        int8v a[4], b[4];
        #pragma unroll
        for (int i = 0; i < 4; ++i) {
            const int r = wr * 64 + i * 16 + lr;
            const unsigned char* pA = As + r * BK + ((lq ^ (lr & 3)) << 5);
            int4v lo = *(const int4v*)pA;
            int4v hi = *(const int4v*)(pA + 16);
            a[i] = __builtin_shufflevector(lo, hi, 0, 1, 2, 3, 4, 5, 6, 7);
        }
        #pragma unroll
        for (int j = 0; j < 4; ++j) {
            const int r = wc * 64 + j * 16 + lr;
            const unsigned char* pB = Bs + r * BK + ((lq ^ (lr & 3)) << 5);
            int4v lo = *(const int4v*)pB;
            int4v hi = *(const int4v*)(pB + 16);
            b[j] = __builtin_shufflevector(lo, hi, 0, 1, 2, 3, 4, 5, 6, 7);
        }
        #pragma unroll
        for (int i = 0; i < 4; ++i)
            #pragma unroll
            for (int j = 0; j < 4; ++j)
                acc[i][j] = __builtin_amdgcn_mfma_scale_f32_16x16x128_f8f6f4(
                    a[i], b[j], acc[i][j], 0, 0,      // cbsz=0 (fp8), blgp=0 (fp8)
                    0, 0x7f7f7f7f, 0, 0x7f7f7f7f);    // unit E8M0 scales
        __syncthreads();
    }

    // ---- fused stage-2 epilogue: P[rb][col] = sum_h acc * ey(m,h) ----
    const int c  = row0 / CSTRIDE;   // block-uniform (CSTRIDE = 3*128)
    const int h0 = row0 - c * CSTRIDE;

    #pragma unroll
    for (int j = 0; j < 4; ++j) {
        const int jcol = wc * 64 + j * 16 + lr;
        const int m = (col0 + jcol) & (MM - 1);
        const float om0 = omega[m];
        float ss, sc;
        __sincosf(TWO_PI * om0, &ss, &sc);
        const float str = sc, sti = -ss;               // step = exp(-2pi i om0)
        // step^16 via 4 complex squarings (saves 3 sincos per j vs per-i sincos)
        float s2r = str * str - sti * sti, s2i = 2.0f * str * sti;
        float s4r = s2r * s2r - s2i * s2i, s4i = 2.0f * s2r * s2i;
        float s8r = s4r * s4r - s4i * s4i, s8i = 2.0f * s4r * s4i;
        float s16r = s8r * s8r - s8i * s8i, s16i = 2.0f * s8r * s8i;

        const int hb0 = h0 + wr * 64 + lq * 4;
        float sn, cs;
        __sincosf(TWO_PI * om0 * (float)(hb0 - 150), &sn, &cs);
        float byr = cs, byi = -sn;                     // ey at h = hb0 (i-block base)

        float pr = 0.0f, pi = 0.0f;
        #pragma unroll
        for (int i = 0; i < 4; ++i) {
            float er = byr, ei = byi;
            #pragma unroll
            for (int r = 0; r < 4; ++r) {
                const float v = acc[i][j][r];
                pr = fmaf(v, er, pr);
                pi = fmaf(v, ei, pi);
                float nr = er * str - ei * sti;
                ei = er * sti + ei * str;
                er = nr;
            }
            float nbr = byr * s16r - byi * s16i;       // advance base by 16 rows
            byi = byr * s16i + byi * s16r;
            byr = nbr;
        }
        pr += __shfl_down(pr, 32); pi += __shfl_down(pi, 32);
        pr += __shfl_down(pr, 16); pi += __shfl_down(pi, 16);
        if (lq == 0) {
            atomicAdd(&red[jcol].x, pr);
            atomicAdd(&red[jcol].y, pi);
        }
    }
    __syncthreads();

    if (t < 128) {
        const int rb = row0 >> 7;
        P[(size_t)rb * NP + col0 + t] = red[t];
    }
}

// loss: k[c,m] from 3 row-block partials. 256 blocks x 64 threads (one wave each)
// to spread the latency-bound strided P reads across all CUs.
__global__ __launch_bounds__(64) void loss_kernel(
    const float2* __restrict__ P, const float* __restrict__ kdata,
    const float* __restrict__ omega, float* __restrict__ out)
{
    const int t = blockIdx.x * 64 + threadIdx.x;   // 0..16383
    const int c = t >> 12;
    const int m = t & (MM - 1);

    float kr = 0.0f, ki = 0.0f;
    #pragma unroll
    for (int q = 0; q < 3; ++q) {
        const int rb = 3 * c + q;
        float2 p0 = P[(size_t)rb * NP + m];          // real-col partial
        float2 p1 = P[(size_t)rb * NP + m + MM];     // imag-col partial
        kr += p0.x - p1.y;
        ki += p0.y + p1.x;
    }
    kr *= (1.0f / 300.0f);
    ki *= (1.0f / 300.0f);

    const float om0 = omega[m];
    const float om1 = omega[MM + m];
    const size_t kidx = ((size_t)c * MM + m) * 2;
    const float kdr = kdata[kidx];
    const float kdi = kdata[kidx + 1];
    const float w0 = om0 * TWO_PI, w1 = om1 * TWO_PI;
    const float wg = sqrtf(w0 * w0 + w1 * w1) + 1.0f;
    const float dr = wg * (kr - kdr);
    const float di = wg * (ki - kdi);
    float val = (dr * dr + di * di) * (1.0f / (2.0f * CC * MM));

    #pragma unroll
    for (int off = 32; off > 0; off >>= 1) val += __shfl_down(val, off);
    if (threadIdx.x == 0) atomicAdd(out, val);
}

extern "C" void kernel_launch(void* const* d_in, const int* in_sizes, int n_in,
                              void* d_out, int out_size, void* d_ws, size_t ws_size,
                              hipStream_t stream) {
    const float* img   = (const float*)d_in[0];   // (300,300,1)
    const float* kdata = (const float*)d_in[1];   // (1,4,4096,2)
    const float* omega = (const float*)d_in[2];   // (1,2,4096)
    const float* csm   = (const float*)d_in[4];   // (4,300,300,2)
    float* out = (float*)d_out;

    unsigned char* Aws = (unsigned char*)d_ws;                  // MP*KP  = 0.98 MB
    unsigned char* Bws = (unsigned char*)d_ws + (1u << 20);     // NP*KP  = 5.24 MB
    float2*        Pws = (float2*)((char*)d_ws + (8u << 20));   // NRB*NP*8 = 786 KB

    const int ablk = (MP * KP / 2) / 256;      // 1920
    const int bblk = (MM * 160) / 256;         // 2560
    prep_kernel<<<ablk + bblk, 256, 0, stream>>>(img, csm, omega,
                                                 (ushort*)Aws, Bws, out);
    gemm_kernel<<<dim3(NP / 128, MP / 128), 256, 0, stream>>>(Aws, Bws, omega, Pws);
    loss_kernel<<<CC * MM / 64, 64, 0, stream>>>(Pws, kdata, omega, out);
}

// Round 7
// 84.016 us; speedup vs baseline: 1.7669x; 1.0685x over previous
//
#include <hip/hip_runtime.h>
#include <math.h>

#define HH 300
#define WW 300
#define CC 4
#define MM 4096
#define KP 640          // padded K (fp8 bytes/row), 2*W=600 -> 640
#define NKC (KP/32)     // 20 k-chunks of 32 B
#define CSTRIDE 384     // per-coil row stride (3*128: every 128-row tile coil-pure)
#define MP (CC*CSTRIDE) // 1536
#define NP 8192         // 2*M (real | imag output columns)
#define NRB (MP/128)    // 12 row-blocks

typedef __attribute__((ext_vector_type(4))) float f32x4;
typedef __attribute__((ext_vector_type(4))) int int4v;
typedef __attribute__((ext_vector_type(8))) int int8v;

#define TWO_PI 6.283185307179586f

// Chunk-major element address: elem (row, k) of an R-row matrix lives at
// ((k/32)*R + row)*32 + (k%32). Fragment loads (16 rows x 32 B per lq-group)
// are then 8 contiguous 128-B segments per wave -> fully coalesced.
__device__ __forceinline__ size_t cmaddr(int R, int row, int k) {
    return ((size_t)(k >> 5) * R + row) * 32 + (k & 31);
}

// A value at (row, k): row = c*CSTRIDE + h; k<300 -> sim_r[w=k]; 300<=k<600 -> sim_i; else 0
__device__ __forceinline__ float aval(const float* img, const float* csm,
                                      int c, int h, int k) {
    if (k >= 2 * WW) return 0.0f;
    int w = (k < WW) ? k : k - WW;
    float im = img[h * WW + w];
    const float* cs = csm + (((size_t)c * HH + h) * WW + w) * 2;
    return ((k < WW) ? cs[0] : cs[1]) * im;
}

// prep: zero out[0], build A (MP x KP fp8 e4m3, chunk-major) and B^T (NP x KP fp8,
// chunk-major). B row m (real col) = [ez_r | -ez_i | 0pad]; row m+4096 (imag col)
// = [ez_i | ez_r | 0pad]. One thread per w-pair computes sincos once, writes 4 spots.
__global__ __launch_bounds__(256) void prep_kernel(
    const float* __restrict__ img, const float* __restrict__ csm,
    const float* __restrict__ omega, unsigned char* __restrict__ A,
    unsigned char* __restrict__ B, float* __restrict__ out)
{
    const int bid = blockIdx.x;
    if (bid == 0 && threadIdx.x == 0) out[0] = 0.0f;
    const int ABLK = (MP * KP / 2) / 256;   // 1920
    if (bid < ABLK) {
        int idx = bid * 256 + threadIdx.x;            // pair index
        int row = idx / (KP / 2);
        int k   = (idx - row * (KP / 2)) * 2;
        int c = row / CSTRIDE;
        int h = row - c * CSTRIDE;
        float v0 = 0.0f, v1 = 0.0f;
        if (h < HH) { v0 = aval(img, csm, c, h, k); v1 = aval(img, csm, c, h, k + 1); }
        int pk = __builtin_amdgcn_cvt_pk_fp8_f32(v0, v1, 0, false);
        *(ushort*)(A + cmaddr(MP, row, k)) = (ushort)pk;   // k even: pair stays in chunk
    } else {
        int idx = (bid - ABLK) * 256 + threadIdx.x;   // 0 .. 4096*160-1
        int m  = idx / 160;
        int wp = idx - m * 160;
        if (wp < 150) {
            int w = wp * 2;
            float om1 = omega[MM + m];
            float s0, c0, s1, c1;
            __sincosf(TWO_PI * om1 * (float)(w - 150), &s0, &c0);
            __sincosf(TWO_PI * om1 * (float)(w - 149), &s1, &c1);
            // ez = exp(-i th): ez_r = cos, ez_i = -sin
            ushort rr = (ushort)__builtin_amdgcn_cvt_pk_fp8_f32(c0, c1, 0, false);
            ushort ii = (ushort)__builtin_amdgcn_cvt_pk_fp8_f32(-s0, -s1, 0, false);
            ushort ni = (ushort)__builtin_amdgcn_cvt_pk_fp8_f32(s0, s1, 0, false); // -ez_i
            *(ushort*)(B + cmaddr(NP, m,      w))        = rr;  // real col, ez_r
            *(ushort*)(B + cmaddr(NP, m,      WW + w))   = ni;  // real col, -ez_i
            *(ushort*)(B + cmaddr(NP, m + MM, w))        = ii;  // imag col, ez_i
            *(ushort*)(B + cmaddr(NP, m + MM, WW + w))   = rr;  // imag col, ez_r
        } else {
            int k = 600 + (wp - 150) * 4;             // 600..636, 4-B aligned in-chunk
            *(unsigned int*)(B + cmaddr(NP, m,      k)) = 0u;
            *(unsigned int*)(B + cmaddr(NP, m + MM, k)) = 0u;
        }
    }
}

// Barrier-free fp8 MX GEMM: fragments loaded global->VGPR directly (chunk-major,
// coalesced), no LDS staging, no __syncthreads in the K-loop. Fused ey-rotation
// epilogue with one barrier pair at the end.
__global__ __launch_bounds__(256) void gemm_kernel(
    const unsigned char* __restrict__ A, const unsigned char* __restrict__ B,
    const float* __restrict__ omega, float2* __restrict__ P)
{
    __shared__ float2 red[128];

    const int t    = threadIdx.x;
    const int wave = t >> 6;
    const int ln   = t & 63;
    const int row0 = blockIdx.y * 128;
    const int col0 = blockIdx.x * 128;
    const int wr = wave >> 1, wc = wave & 1;
    const int lr = ln & 15;
    const int lq = ln >> 4;

    if (t < 128) red[t] = make_float2(0.0f, 0.0f);

    const int arow = row0 + wr * 64 + lr;   // base row for this lane's A frags
    const int bcol = col0 + wc * 64 + lr;   // base col for this lane's B frags

    f32x4 acc[4][4] = {};

    #pragma unroll
    for (int kc = 0; kc < NKC; kc += 4) {   // 5 fully-unrolled K-steps (K=128 each)
        int8v a[4], b[4];
        #pragma unroll
        for (int i = 0; i < 4; ++i) {
            const unsigned char* pA = A + ((size_t)(kc + lq) * MP + arow + i * 16) * 32;
            int4v lo = *(const int4v*)pA;
            int4v hi = *(const int4v*)(pA + 16);
            a[i] = __builtin_shufflevector(lo, hi, 0, 1, 2, 3, 4, 5, 6, 7);
        }
        #pragma unroll
        for (int j = 0; j < 4; ++j) {
            const unsigned char* pB = B + ((size_t)(kc + lq) * NP + bcol + j * 16) * 32;
            int4v lo = *(const int4v*)pB;
            int4v hi = *(const int4v*)(pB + 16);
            b[j] = __builtin_shufflevector(lo, hi, 0, 1, 2, 3, 4, 5, 6, 7);
        }
        #pragma unroll
        for (int i = 0; i < 4; ++i)
            #pragma unroll
            for (int j = 0; j < 4; ++j)
                acc[i][j] = __builtin_amdgcn_mfma_scale_f32_16x16x128_f8f6f4(
                    a[i], b[j], acc[i][j], 0, 0,      // cbsz=0 (fp8), blgp=0 (fp8)
                    0, 0x7f7f7f7f, 0, 0x7f7f7f7f);    // unit E8M0 scales
    }

    __syncthreads();   // red[] init visible before epilogue atomics

    // ---- fused stage-2 epilogue: P[rb][col] = sum_h acc * ey(m,h) ----
    const int c  = row0 / CSTRIDE;   // block-uniform (CSTRIDE = 3*128)
    const int h0 = row0 - c * CSTRIDE;

    #pragma unroll
    for (int j = 0; j < 4; ++j) {
        const int jcol = wc * 64 + j * 16 + lr;
        const int m = (col0 + jcol) & (MM - 1);
        const float om0 = omega[m];
        float ss, sc;
        __sincosf(TWO_PI * om0, &ss, &sc);
        const float str = sc, sti = -ss;               // step = exp(-2pi i om0)
        float s2r = str * str - sti * sti, s2i = 2.0f * str * sti;
        float s4r = s2r * s2r - s2i * s2i, s4i = 2.0f * s2r * s2i;
        float s8r = s4r * s4r - s4i * s4i, s8i = 2.0f * s4r * s4i;
        float s16r = s8r * s8r - s8i * s8i, s16i = 2.0f * s8r * s8i;

        const int hb0 = h0 + wr * 64 + lq * 4;
        float sn, cs;
        __sincosf(TWO_PI * om0 * (float)(hb0 - 150), &sn, &cs);
        float byr = cs, byi = -sn;                     // ey at h = hb0

        float pr = 0.0f, pi = 0.0f;
        #pragma unroll
        for (int i = 0; i < 4; ++i) {
            float er = byr, ei = byi;
            #pragma unroll
            for (int r = 0; r < 4; ++r) {
                const float v = acc[i][j][r];
                pr = fmaf(v, er, pr);
                pi = fmaf(v, ei, pi);
                float nr = er * str - ei * sti;
                ei = er * sti + ei * str;
                er = nr;
            }
            float nbr = byr * s16r - byi * s16i;       // advance base by 16 rows
            byi = byr * s16i + byi * s16r;
            byr = nbr;
        }
        pr += __shfl_down(pr, 32); pi += __shfl_down(pi, 32);
        pr += __shfl_down(pr, 16); pi += __shfl_down(pi, 16);
        if (lq == 0) {
            atomicAdd(&red[jcol].x, pr);
            atomicAdd(&red[jcol].y, pi);
        }
    }
    __syncthreads();

    if (t < 128) {
        const int rb = row0 >> 7;
        P[(size_t)rb * NP + col0 + t] = red[t];
    }
}

// loss: k[c,m] from 3 row-block partials. 256 blocks x 64 threads (one wave each).
__global__ __launch_bounds__(64) void loss_kernel(
    const float2* __restrict__ P, const float* __restrict__ kdata,
    const float* __restrict__ omega, float* __restrict__ out)
{
    const int t = blockIdx.x * 64 + threadIdx.x;   // 0..16383
    const int c = t >> 12;
    const int m = t & (MM - 1);

    float kr = 0.0f, ki = 0.0f;
    #pragma unroll
    for (int q = 0; q < 3; ++q) {
        const int rb = 3 * c + q;
        float2 p0 = P[(size_t)rb * NP + m];          // real-col partial
        float2 p1 = P[(size_t)rb * NP + m + MM];     // imag-col partial
        kr += p0.x - p1.y;
        ki += p0.y + p1.x;
    }
    kr *= (1.0f / 300.0f);
    ki *= (1.0f / 300.0f);

    const float om0 = omega[m];
    const float om1 = omega[MM + m];
    const size_t kidx = ((size_t)c * MM + m) * 2;
    const float kdr = kdata[kidx];
    const float kdi = kdata[kidx + 1];
    const float w0 = om0 * TWO_PI, w1 = om1 * TWO_PI;
    const float wg = sqrtf(w0 * w0 + w1 * w1) + 1.0f;
    const float dr = wg * (kr - kdr);
    const float di = wg * (ki - kdi);
    float val = (dr * dr + di * di) * (1.0f / (2.0f * CC * MM));

    #pragma unroll
    for (int off = 32; off > 0; off >>= 1) val += __shfl_down(val, off);
    if (threadIdx.x == 0) atomicAdd(out, val);
}

extern "C" void kernel_launch(void* const* d_in, const int* in_sizes, int n_in,
                              void* d_out, int out_size, void* d_ws, size_t ws_size,
                              hipStream_t stream) {
    const float* img   = (const float*)d_in[0];   // (300,300,1)
    const float* kdata = (const float*)d_in[1];   // (1,4,4096,2)
    const float* omega = (const float*)d_in[2];   // (1,2,4096)
    const float* csm   = (const float*)d_in[4];   // (4,300,300,2)
    float* out = (float*)d_out;

    unsigned char* Aws = (unsigned char*)d_ws;                  // MP*KP  = 0.98 MB
    unsigned char* Bws = (unsigned char*)d_ws + (1u << 20);     // NP*KP  = 5.24 MB
    float2*        Pws = (float2*)((char*)d_ws + (8u << 20));   // NRB*NP*8 = 786 KB

    const int ablk = (MP * KP / 2) / 256;      // 1920
    const int bblk = (MM * 160) / 256;         // 2560
    prep_kernel<<<ablk + bblk, 256, 0, stream>>>(img, csm, omega, Aws, Bws, out);
    gemm_kernel<<<dim3(NP / 128, MP / 128), 256, 0, stream>>>(Aws, Bws, omega, Pws);
    loss_kernel<<<CC * MM / 64, 64, 0, stream>>>(Pws, kdata, omega, out);
}